// Round 1
// baseline (659.514 us; speedup 1.0000x reference)
//
#include <hip/hip_runtime.h>
#include <hip/hip_bf16.h>

#define HID 1024
#define BATCH 32
#define SEQ 2048
#define MROWS (BATCH*SEQ)   // 65536

typedef __bf16 bf16x8 __attribute__((ext_vector_type(8)));
typedef float f32x4 __attribute__((ext_vector_type(4)));

__device__ __forceinline__ unsigned short f2bf(float f) {
  unsigned int x = __float_as_uint(f);
  x += 0x7FFFu + ((x >> 16) & 1u);   // RNE
  return (unsigned short)(x >> 16);
}

// ---------------------------------------------------------------------------
// prep: convert Wp (=W_proj[:, :1024]) to bf16 row-major [h][d]; compute
// c[b,h] = dot(current[b,:], Wc[h,:]) + b_proj[h] in fp32.
// grid = 1024 (one block per h), block = 256.
// ---------------------------------------------------------------------------
__global__ __launch_bounds__(256) void prep_kernel(
    const float* __restrict__ cur, const float* __restrict__ Wproj,
    const float* __restrict__ bproj, unsigned short* __restrict__ Bbf,
    float* __restrict__ c_ws)
{
  int h = blockIdx.x, t = threadIdx.x;
  // convert Wp row h (1024 f32 -> bf16), 4 elems/thread
  float4 v = ((const float4*)(Wproj + (long)h * 2048))[t];
  ushort4 u; u.x = f2bf(v.x); u.y = f2bf(v.y); u.z = f2bf(v.z); u.w = f2bf(v.w);
  ((ushort4*)(Bbf + (long)h * 1024))[t] = u;

  // stage Wc row h in LDS
  __shared__ float wc[HID];
  float4 w4 = ((const float4*)(Wproj + (long)h * 2048 + 1024))[t];
  ((float4*)wc)[t] = w4;
  __syncthreads();

  int wv = t >> 6, l = t & 63;
  float bp = bproj[h];
  for (int i = 0; i < 8; ++i) {
    int b = wv * 8 + i;
    const float* cb = cur + b * HID;
    float s = 0.f;
    #pragma unroll
    for (int j = 0; j < 16; ++j) { int d = l + j * 64; s += cb[d] * wc[d]; }
    #pragma unroll
    for (int m = 1; m < 64; m <<= 1) s += __shfl_xor(s, m, 64);
    if (l == 0) c_ws[b * HID + h] = s + bp;
  }
}

// ---------------------------------------------------------------------------
// score GEMM: C[m,n] = sum_k past[m,k]*Wp[n,k]  (m = b*2048+s, n = h, k = d)
// 128x128 tile, BK=64, 4 waves, 16x16x32 bf16 MFMA.
// Epilogue: scores[m] += sum_n w_score[n]*tanh(C[m,n] + c[b,n])  (atomicAdd)
// grid = 512*8 = 4096 blocks (XCD-swizzled), block = 256.
// ---------------------------------------------------------------------------
#define BM 128
#define BN 128
#define BK 64

__global__ __launch_bounds__(256) void score_gemm(
    const float* __restrict__ past, const unsigned short* __restrict__ Bbf,
    const float* __restrict__ c_ws, const float* __restrict__ wsc,
    float* __restrict__ scores)
{
  __shared__ unsigned short As[BM * BK];  // 16 KB, XOR-swizzled
  __shared__ unsigned short Bs[BN * BK];  // 16 KB, XOR-swizzled

  // XCD swizzle: nwg=4096, 8 XCDs -> 512 consecutive wg per XCD.
  // wg -> (mt = wg/8, nt = wg%8): one XCD sees all 8 n-tiles of an A-strip.
  int bid = blockIdx.x;
  int wg = (bid & 7) * 512 + (bid >> 3);
  int mt = wg >> 3, nt = wg & 7;
  long row0 = (long)mt * BM;
  int n0 = nt * BN;
  int b = mt >> 4;              // 2048/128 = 16 m-tiles per batch row

  int t = threadIdx.x;
  int w = t >> 6, lane = t & 63;
  int wr = w >> 1, wcn = w & 1;
  int la = lane & 15, lb = lane >> 4;

  f32x4 acc[4][4] = {};

  for (int kt = 0; kt < HID / BK; ++kt) {
    int k0 = kt * BK;
    // --- A: global f32 loads (issued early, before barrier) ---
    float4 av[8];
    #pragma unroll
    for (int i = 0; i < 8; ++i) {
      int c = t + 256 * i;
      int r = c >> 4, fc = c & 15;
      av[i] = ((const float4*)(past + (row0 + r) * 1024 + k0))[fc];
    }
    __syncthreads();  // previous tile's ds_reads done
    // --- A: convert + swizzled LDS write (8B chunks) ---
    #pragma unroll
    for (int i = 0; i < 8; ++i) {
      int c = t + 256 * i;
      int r = c >> 4, fc = c & 15;
      int off = (r * 128 + fc * 8) ^ ((r & 7) << 4);
      ushort4 uu; uu.x = f2bf(av[i].x); uu.y = f2bf(av[i].y);
      uu.z = f2bf(av[i].z); uu.w = f2bf(av[i].w);
      *(ushort4*)((char*)As + off) = uu;
    }
    // --- B: global_load_lds, linear dest + inverse-swizzled source ---
    #pragma unroll
    for (int i = 0; i < 4; ++i) {
      int o = (t + 256 * i) * 16;
      int uoff = o ^ (((o >> 7) & 7) << 4);   // involution
      int n = uoff >> 7, inb = uoff & 127;
      const unsigned short* src = Bbf + (long)(n0 + n) * 1024 + k0 + (inb >> 1);
      __builtin_amdgcn_global_load_lds(
          (const __attribute__((address_space(1))) void*)src,
          (__attribute__((address_space(3))) void*)((char*)Bs + o), 16, 0, 0);
    }
    __syncthreads();  // compiler drains vmcnt+lgkmcnt before barrier
    // --- compute: 2 sub-K of 32, 4x4 fragments per wave ---
    #pragma unroll
    for (int kk = 0; kk < 2; ++kk) {
      bf16x8 af[4], bfv[4];
      #pragma unroll
      for (int m = 0; m < 4; ++m) {
        int r = wr * 64 + m * 16 + la;
        int off = (r * 128 + kk * 64 + lb * 16) ^ ((r & 7) << 4);
        af[m] = *(const bf16x8*)((const char*)As + off);
      }
      #pragma unroll
      for (int n = 0; n < 4; ++n) {
        int r = wcn * 64 + n * 16 + la;
        int off = (r * 128 + kk * 64 + lb * 16) ^ ((r & 7) << 4);
        bfv[n] = *(const bf16x8*)((const char*)Bs + off);
      }
      #pragma unroll
      for (int m = 0; m < 4; ++m)
        #pragma unroll
        for (int n = 0; n < 4; ++n)
          acc[m][n] = __builtin_amdgcn_mfma_f32_16x16x32_bf16(
              af[m], bfv[n], acc[m][n], 0, 0, 0);
    }
  }

  // --- epilogue: tanh + w_score reduce over this block's 128 h columns ---
  const float* crow = c_ws + b * HID;
  float ch[4], wv4[4];
  #pragma unroll
  for (int n = 0; n < 4; ++n) {
    int h = n0 + wcn * 64 + n * 16 + la;
    ch[n] = crow[h];
    wv4[n] = wsc[h];
  }
  #pragma unroll
  for (int m = 0; m < 4; ++m) {
    #pragma unroll
    for (int j = 0; j < 4; ++j) {
      float rs = 0.f;
      #pragma unroll
      for (int n = 0; n < 4; ++n)
        rs += wv4[n] * tanhf(acc[m][n][j] + ch[n]);
      rs += __shfl_xor(rs, 1, 64);
      rs += __shfl_xor(rs, 2, 64);
      rs += __shfl_xor(rs, 4, 64);
      rs += __shfl_xor(rs, 8, 64);
      if (la == 0) {
        long grow = row0 + wr * 64 + m * 16 + lb * 4 + j;
        atomicAdd(scores + grow, rs);
      }
    }
  }
}

// ---------------------------------------------------------------------------
// softmax over s (in place on scores -> attn weights). grid=32, block=256.
// ---------------------------------------------------------------------------
__global__ __launch_bounds__(256) void softmax_kernel(float* __restrict__ sc)
{
  int b = blockIdx.x, t = threadIdx.x;
  float* row = sc + (long)b * SEQ;
  float v[8]; float mx = -1e30f;
  #pragma unroll
  for (int j = 0; j < 8; ++j) { v[j] = row[t + j * 256]; mx = fmaxf(mx, v[j]); }
  #pragma unroll
  for (int m = 1; m < 64; m <<= 1) mx = fmaxf(mx, __shfl_xor(mx, m, 64));
  __shared__ float rmax[4], rsum[4];
  if ((t & 63) == 0) rmax[t >> 6] = mx;
  __syncthreads();
  mx = fmaxf(fmaxf(rmax[0], rmax[1]), fmaxf(rmax[2], rmax[3]));
  float s = 0.f;
  #pragma unroll
  for (int j = 0; j < 8; ++j) { v[j] = expf(v[j] - mx); s += v[j]; }
  #pragma unroll
  for (int m = 1; m < 64; m <<= 1) s += __shfl_xor(s, m, 64);
  if ((t & 63) == 0) rsum[t >> 6] = s;
  __syncthreads();
  float inv = 1.f / (rsum[0] + rsum[1] + rsum[2] + rsum[3]);
  #pragma unroll
  for (int j = 0; j < 8; ++j) row[t + j * 256] = v[j] * inv;
}

// ---------------------------------------------------------------------------
// attended stage 1: partial[b*16+sc][d] = sum_{s in chunk} attn[b,s]*past[b,s,d]
// grid = 32*16 = 512, block = 256 (each thread owns 4 d's = full 1024 d).
// ---------------------------------------------------------------------------
__global__ __launch_bounds__(256) void attend_partial(
    const float* __restrict__ past, const float* __restrict__ attn,
    float* __restrict__ partial)
{
  int blk = blockIdx.x;
  int b = blk >> 4, scn = blk & 15;
  int t = threadIdx.x;
  int s0 = scn * 128;
  __shared__ float aw[128];
  if (t < 128) aw[t] = attn[(long)b * SEQ + s0 + t];
  __syncthreads();
  const float4* pp = (const float4*)(past + ((long)(b * SEQ + s0)) * HID);
  float ax = 0.f, ay = 0.f, az = 0.f, awv = 0.f;
  #pragma unroll 4
  for (int s = 0; s < 128; ++s) {
    float wgt = aw[s];
    float4 v = pp[s * 256 + t];
    ax += wgt * v.x; ay += wgt * v.y; az += wgt * v.z; awv += wgt * v.w;
  }
  float4 o; o.x = ax; o.y = ay; o.z = az; o.w = awv;
  ((float4*)(partial + (long)blk * HID))[t] = o;
}

// attended stage 2: out[b,d] = sum_sc partial[b*16+sc][d]. grid=128, block=256.
__global__ __launch_bounds__(256) void attend_reduce(
    const float* __restrict__ partial, float* __restrict__ out)
{
  int blk = blockIdx.x;
  int b = blk >> 2, d = (blk & 3) * 256 + threadIdx.x;
  float s = 0.f;
  #pragma unroll
  for (int sc = 0; sc < 16; ++sc) s += partial[(long)(b * 16 + sc) * HID + d];
  out[(long)b * HID + d] = s;
}

// ---------------------------------------------------------------------------
extern "C" void kernel_launch(void* const* d_in, const int* in_sizes, int n_in,
                              void* d_out, int out_size, void* d_ws, size_t ws_size,
                              hipStream_t stream)
{
  const float* cur   = (const float*)d_in[0];  // (32,1024)
  const float* past  = (const float*)d_in[1];  // (32,2048,1024)
  const float* Wproj = (const float*)d_in[2];  // (1024,2048)
  const float* bproj = (const float*)d_in[3];  // (1024,)
  const float* wsc   = (const float*)d_in[4];  // (1024,)

  float* out      = (float*)d_out;
  float* attended = out;            // 32768 floats
  float* scores   = out + 32768;    // 65536 floats: scores -> attn in place

  char* ws = (char*)d_ws;
  float*          c_ws    = (float*)ws;                          // 128 KB
  unsigned short* Bbf     = (unsigned short*)(ws + (128 << 10)); // 2 MB
  float*          partial = (float*)(ws + (128 << 10) + (2 << 20)); // 2 MB

  hipMemsetAsync(scores, 0, (size_t)BATCH * SEQ * sizeof(float), stream);
  prep_kernel<<<1024, 256, 0, stream>>>(cur, Wproj, bproj, Bbf, c_ws);
  score_gemm<<<4096, 256, 0, stream>>>(past, Bbf, c_ws, wsc, scores);
  softmax_kernel<<<BATCH, 256, 0, stream>>>(scores);
  attend_partial<<<512, 256, 0, stream>>>(past, scores, partial);
  attend_reduce<<<128, 256, 0, stream>>>(partial, attended);
}